// Round 8
// baseline (745.920 us; speedup 1.0000x reference)
//
#include <hip/hip_runtime.h>
#include <hip/hip_bf16.h>

// ---------------------------------------------------------------------------
// Problem constants (fixed by the reference setup)
// ---------------------------------------------------------------------------
#define N0   1500000
#define N1   200000
#define N2   20000
#define NB   4096
#define D_IN 100
#define D_H  256
#define D_OUT 47

#define K0P  224   // padded K for layer 0 (100+100 -> 224, mult of 32)
#define K12P 512   // K for layers 1/2 (256+256)

#define NTOT (N1 + N2 + NB)     // concatenated row space (L0|L1|L2)
#define SCAN_BLOCKS 256

typedef __bf16 bf16x8 __attribute__((ext_vector_type(8)));
typedef __bf16 bf16x4 __attribute__((ext_vector_type(4)));
typedef float  f32x4  __attribute__((ext_vector_type(4)));

// ---------------------------------------------------------------------------
// Batched CSR build over all 3 layers: one histogram, one scan, one scatter.
// Row space concatenated L0|L1|L2; since all L0 rows precede L1 rows, the
// csr_src regions per layer are automatically contiguous ([0,E0), [E0,E0+E1)..)
// ---------------------------------------------------------------------------
__global__ void hist_all(const int* __restrict__ dst0, int E0,
                         const int* __restrict__ dst1, int E1,
                         const int* __restrict__ dst2, int E2,
                         int* __restrict__ deg)
{
    int i = blockIdx.x * blockDim.x + threadIdx.x;
    int t;
    if (i < E0)            t = dst0[i];
    else if (i < E0 + E1)  t = N1 + dst1[i - E0];
    else if (i < E0 + E1 + E2) t = N1 + N2 + dst2[i - E0 - E1];
    else return;
    atomicAdd(&deg[t], 1);
}

__global__ __launch_bounds__(256)
void scan_partial(const int* __restrict__ deg, int* __restrict__ partials, int n)
{
    const int b = blockIdx.x;
    const int chunk = (n + gridDim.x - 1) / gridDim.x;
    const int begin = b * chunk;
    const int end = min(begin + chunk, n);

    int s = 0;
    for (int i = begin + threadIdx.x; i < end; i += blockDim.x) s += deg[i];

    #pragma unroll
    for (int o = 32; o > 0; o >>= 1) s += __shfl_down(s, o);
    __shared__ int wsum[4];
    if ((threadIdx.x & 63) == 0) wsum[threadIdx.x >> 6] = s;
    __syncthreads();
    if (threadIdx.x == 0)
        partials[b] = wsum[0] + wsum[1] + wsum[2] + wsum[3];
}

__global__ __launch_bounds__(256)
void scan_offsets(int* __restrict__ partials, int* __restrict__ rowstart, int n)
{
    __shared__ int sm[256];
    const int t = threadIdx.x;
    sm[t] = partials[t];
    __syncthreads();
    for (int d = 1; d < 256; d <<= 1) {
        int val = sm[t];
        int oth = (t >= d) ? sm[t - d] : 0;
        __syncthreads();
        sm[t] = val + oth;
        __syncthreads();
    }
    partials[t] = (t > 0) ? sm[t - 1] : 0;
    if (t == 0) rowstart[n] = sm[255];
}

__global__ __launch_bounds__(256)
void scan_apply(const int* __restrict__ deg, const int* __restrict__ offsets,
                int* __restrict__ rowstart, int n)
{
    const int b = blockIdx.x;
    const int chunk = (n + gridDim.x - 1) / gridDim.x;
    const int begin = b * chunk;
    const int end = min(begin + chunk, n);

    __shared__ int sm[256];
    const int sub = (chunk + blockDim.x - 1) / blockDim.x;
    const int tb = begin + threadIdx.x * sub;
    const int te = min(tb + sub, end);

    int s = 0;
    for (int i = tb; i < te; ++i) s += deg[i];
    sm[threadIdx.x] = s;
    __syncthreads();
    for (int d = 1; d < 256; d <<= 1) {
        int val = sm[threadIdx.x];
        int oth = (threadIdx.x >= d) ? sm[threadIdx.x - d] : 0;
        __syncthreads();
        sm[threadIdx.x] = val + oth;
        __syncthreads();
    }
    int run = offsets[b] + ((threadIdx.x > 0) ? sm[threadIdx.x - 1] : 0);
    for (int i = tb; i < te; ++i) { rowstart[i] = run; run += deg[i]; }
}

__global__ void scatter_all(const int* __restrict__ src0, const int* __restrict__ dst0, int E0,
                            const int* __restrict__ src1, const int* __restrict__ dst1, int E1,
                            const int* __restrict__ src2, const int* __restrict__ dst2, int E2,
                            const int* __restrict__ rowstart,
                            int* __restrict__ cursor,
                            int* __restrict__ csr_src)
{
    int i = blockIdx.x * blockDim.x + threadIdx.x;
    int t, s;
    if (i < E0)                { t = dst0[i];                 s = src0[i]; }
    else if (i < E0 + E1)      { t = N1 + dst1[i - E0];       s = src1[i - E0]; }
    else if (i < E0 + E1 + E2) { t = N1 + N2 + dst2[i - E0 - E1]; s = src2[i - E0 - E1]; }
    else return;
    int pos = rowstart[t] + atomicAdd(&cursor[t], 1);
    csr_src[pos] = s;
}

// ---------------------------------------------------------------------------
// Layer-0 gather+pack: A0[row] = [ mean(x[srcs]) (100) | x[row] (100) | 0 ]
// 4 rows per wave x 4 edges deep: 16 independent 400B row-reads in flight,
// all control flow wave-uniform (row bounds are per-wave scalars). This
// breaks the serial idx->row dependent chain that capped the 1-row version.
// ---------------------------------------------------------------------------
__global__ __launch_bounds__(256)
void gather_pack_l0(const float* __restrict__ x,
                    const int* __restrict__ rowstart,
                    const int* __restrict__ csr,
                    __bf16* __restrict__ A0, int nrows)
{
    const int wid  = (blockIdx.x * blockDim.x + threadIdx.x) >> 6;
    const int lane = threadIdx.x & 63;
    const int r0 = wid * 4;
    if (r0 >= nrows) return;

    const bool act = lane < D_IN / 2;      // 50 lanes x float2
    const int f = lane * 2;
    const float* xf = x + f;

    int cur[4], end_[4];
    #pragma unroll
    for (int i = 0; i < 4; ++i) {
        int r = r0 + i;
        cur[i]  = (r < nrows) ? rowstart[r] : 0;
        end_[i] = (r < nrows) ? rowstart[r + 1] : 0;
    }
    int deg[4];
    #pragma unroll
    for (int i = 0; i < 4; ++i) deg[i] = end_[i] - cur[i];

    float accx[4], accy[4];
    #pragma unroll
    for (int i = 0; i < 4; ++i) { accx[i] = 0.0f; accy[i] = 0.0f; }

    while ((cur[0] < end_[0]) | (cur[1] < end_[1]) |
           (cur[2] < end_[2]) | (cur[3] < end_[3])) {
        float2 v[4][4];
        #pragma unroll
        for (int i = 0; i < 4; ++i)
            #pragma unroll
            for (int s = 0; s < 4; ++s) { v[i][s].x = 0.0f; v[i][s].y = 0.0f; }

        #pragma unroll
        for (int i = 0; i < 4; ++i) {
            #pragma unroll
            for (int s = 0; s < 4; ++s) {
                if (cur[i] + s < end_[i]) {            // wave-uniform branch
                    int idx = csr[cur[i] + s];
                    if (act)
                        v[i][s] = *reinterpret_cast<const float2*>(xf + (long)idx * D_IN);
                }
            }
        }
        #pragma unroll
        for (int i = 0; i < 4; ++i) {
            accx[i] += (v[i][0].x + v[i][1].x) + (v[i][2].x + v[i][3].x);
            accy[i] += (v[i][0].y + v[i][1].y) + (v[i][2].y + v[i][3].y);
            cur[i] = min(cur[i] + 4, end_[i]);
        }
    }

    #pragma unroll
    for (int i = 0; i < 4; ++i) {
        int r = r0 + i;
        if (r >= nrows) break;
        const float inv = 1.0f / fmaxf((float)deg[i], 1.0f);
        __bf16* o = A0 + (long)r * K0P;
        if (act) {
            o[f]     = (__bf16)(accx[i] * inv);
            o[f + 1] = (__bf16)(accy[i] * inv);
            float2 d = *reinterpret_cast<const float2*>(x + (long)r * D_IN + f);
            o[D_IN + f]     = (__bf16)d.x;
            o[D_IN + f + 1] = (__bf16)d.y;
        }
        if (lane < K0P - 2 * D_IN) o[2 * D_IN + lane] = (__bf16)0.0f;
    }
}

// ---------------------------------------------------------------------------
// Layers 1/2 gather+pack (D=256 bf16): Ap = [ mean | h ], unrolled x8.
// (h0/h1 are L3-resident at 102/10 MB; latency is L2/L3-class, x8 suffices.)
// ---------------------------------------------------------------------------
__global__ __launch_bounds__(256)
void gather_pack_h(const __bf16* __restrict__ h,
                   const int* __restrict__ rowstart,
                   const int* __restrict__ csr_src,
                   __bf16* __restrict__ Ap, int nrows)
{
    const int wid  = (blockIdx.x * blockDim.x + threadIdx.x) >> 6;
    const int lane = threadIdx.x & 63;
    if (wid >= nrows) return;

    const int beg = rowstart[wid];
    const int end = rowstart[wid + 1];
    const __bf16* hf = h + lane * 4;

    float acc[8][4];
    #pragma unroll
    for (int u = 0; u < 8; ++u)
        #pragma unroll
        for (int k = 0; k < 4; ++k) acc[u][k] = 0.0f;

    int e = beg;
    for (; e + 8 <= end; e += 8) {
        int idx[8];
        #pragma unroll
        for (int u = 0; u < 8; ++u) idx[u] = csr_src[e + u];
        bf16x4 v[8];
        #pragma unroll
        for (int u = 0; u < 8; ++u)
            v[u] = *reinterpret_cast<const bf16x4*>(hf + (long)idx[u] * D_H);
        #pragma unroll
        for (int u = 0; u < 8; ++u)
            #pragma unroll
            for (int k = 0; k < 4; ++k) acc[u][k] += (float)v[u][k];
    }
    for (; e + 4 <= end; e += 4) {
        int idx[4];
        #pragma unroll
        for (int u = 0; u < 4; ++u) idx[u] = csr_src[e + u];
        bf16x4 v[4];
        #pragma unroll
        for (int u = 0; u < 4; ++u)
            v[u] = *reinterpret_cast<const bf16x4*>(hf + (long)idx[u] * D_H);
        #pragma unroll
        for (int u = 0; u < 4; ++u)
            #pragma unroll
            for (int k = 0; k < 4; ++k) acc[u][k] += (float)v[u][k];
    }
    for (; e < end; ++e) {
        bf16x4 v = *reinterpret_cast<const bf16x4*>(hf + (long)csr_src[e] * D_H);
        #pragma unroll
        for (int k = 0; k < 4; ++k) acc[0][k] += (float)v[k];
    }

    const float inv = 1.0f / fmaxf((float)(end - beg), 1.0f);
    bf16x4 m;
    #pragma unroll
    for (int k = 0; k < 4; ++k) {
        float s = ((acc[0][k] + acc[1][k]) + (acc[2][k] + acc[3][k]))
                + ((acc[4][k] + acc[5][k]) + (acc[6][k] + acc[7][k]));
        m[k] = (__bf16)(s * inv);
    }
    *reinterpret_cast<bf16x4*>(Ap + (long)wid * K12P + lane * 4) = m;

    bf16x4 own = *reinterpret_cast<const bf16x4*>(h + (long)wid * D_H + lane * 4);
    *reinterpret_cast<bf16x4*>(Ap + (long)wid * K12P + D_H + lane * 4) = own;
}

// ---------------------------------------------------------------------------
// Weight pack (all 3 layers in one launch): Wp[n][k] bf16, B^T layout.
// ---------------------------------------------------------------------------
__global__ void pack_weights_all(const float* __restrict__ Wl0, const float* __restrict__ Wr0, __bf16* __restrict__ Wp0,
                                 const float* __restrict__ Wl1, const float* __restrict__ Wr1, __bf16* __restrict__ Wp1,
                                 const float* __restrict__ Wl2, const float* __restrict__ Wr2, __bf16* __restrict__ Wp2)
{
    int b = blockIdx.x;
    const float* Wl; const float* Wr; __bf16* Wp;
    int K1, N, Kpad, n;
    if (b < 256)      { Wl = Wl0; Wr = Wr0; Wp = Wp0; K1 = D_IN; N = D_H;   Kpad = K0P;  n = b; }
    else if (b < 512) { Wl = Wl1; Wr = Wr1; Wp = Wp1; K1 = D_H;  N = D_H;   Kpad = K12P; n = b - 256; }
    else              { Wl = Wl2; Wr = Wr2; Wp = Wp2; K1 = D_H;  N = D_OUT; Kpad = K12P; n = b - 512; }

    for (int k = threadIdx.x; k < Kpad; k += blockDim.x) {
        float v = 0.0f;
        if (n < N) {
            if (k < K1)            v = Wl[(long)k * N + n];
            else if (k < 2 * K1)   v = Wr[(long)(k - K1) * N + n];
        }
        Wp[(long)n * Kpad + k] = (__bf16)v;
    }
}

// ---------------------------------------------------------------------------
// bf16 MFMA GEMM: C[M][Nreal] = act(A[M][K] @ Bt[Npad][K]^T + bias)
// Staging via global_load_lds dwordx4, linear LDS (proven R7, -24 us).
// ---------------------------------------------------------------------------
#define BM 128
#define BK 32

template <int BN_T, int NT>
__global__ __launch_bounds__(NT)
void mfma_gemm(const __bf16* __restrict__ A,
               const __bf16* __restrict__ Bt,
               const float* __restrict__ bias,
               __bf16* __restrict__ Cbf,
               float* __restrict__ Cf,
               int M, int K, int Nreal, int relu)
{
    constexpr int WC = (NT / 64) / 2;               // column waves
    static_assert(WC * 64 == BN_T, "wave grid must cover BN_T");
    constexpr int SIT = (BM + BN_T) * 4 / NT;       // staging iters (16B chunks)
    static_assert((BM * 4) % 64 == 0, "A/B staging boundary must be wave-aligned");

    __shared__ __bf16 S[(BM + BN_T) * BK];          // linear: row r at S[r*32]

    const int tid  = threadIdx.x;
    const int lane = tid & 63;
    const int wv   = tid >> 6;
    const int wr   = wv / WC;
    const int wc   = wv % WC;
    const long row0 = (long)blockIdx.x * BM;
    const int  col0 = blockIdx.y * BN_T;

    f32x4 acc[4][4] = {};

    for (int k0 = 0; k0 < K; k0 += BK) {
        __syncthreads();
        #pragma unroll
        for (int i = 0; i < SIT; ++i) {
            int c  = tid + i * NT;
            int r  = c >> 2;
            int ko = (c & 3) * 8;
            const __bf16* g;
            if (r < BM) {
                long gr = row0 + r;
                if (gr > M - 1) gr = M - 1;
                g = &A[gr * K + k0 + ko];
            } else {
                g = &Bt[(long)(col0 + (r - BM)) * K + k0 + ko];
            }
            __bf16* ldsb = &S[(size_t)(i * NT + wv * 64) * 8];
            __builtin_amdgcn_global_load_lds(
                (const __attribute__((address_space(1))) void*)g,
                (__attribute__((address_space(3))) void*)ldsb,
                16, 0, 0);
        }
        __syncthreads();

        bf16x8 a[4], b[4];
        #pragma unroll
        for (int mi = 0; mi < 4; ++mi)
            a[mi] = *reinterpret_cast<const bf16x8*>(
                &S[(wr * 64 + mi * 16 + (lane & 15)) * BK + (lane >> 4) * 8]);
        #pragma unroll
        for (int ni = 0; ni < 4; ++ni)
            b[ni] = *reinterpret_cast<const bf16x8*>(
                &S[(BM + wc * 64 + ni * 16 + (lane & 15)) * BK + (lane >> 4) * 8]);

        #pragma unroll
        for (int mi = 0; mi < 4; ++mi)
            #pragma unroll
            for (int ni = 0; ni < 4; ++ni)
                acc[mi][ni] = __builtin_amdgcn_mfma_f32_16x16x32_bf16(
                    a[mi], b[ni], acc[mi][ni], 0, 0, 0);
    }

    const int colBase = col0 + wc * 64;
    #pragma unroll
    for (int mi = 0; mi < 4; ++mi) {
        const long rowBase = row0 + wr * 64 + mi * 16 + (lane >> 4) * 4;
        #pragma unroll
        for (int j = 0; j < 4; ++j) {
            long r = rowBase + j;
            if (r >= M) continue;
            #pragma unroll
            for (int ni = 0; ni < 4; ++ni) {
                int cc = colBase + ni * 16 + (lane & 15);
                if (cc >= Nreal) continue;
                float v = acc[mi][ni][j] + bias[cc];
                if (relu) v = fmaxf(v, 0.0f);
                if (Cbf) Cbf[r * Nreal + cc] = (__bf16)v;
                else     Cf [r * Nreal + cc] = v;
            }
        }
    }
}

// ---------------------------------------------------------------------------
// Row-wise log_softmax: one wave per row, cols <= 64
// ---------------------------------------------------------------------------
__global__ void log_softmax_kernel(const float* __restrict__ in,
                                   float* __restrict__ out,
                                   int rows, int cols)
{
    int wave = (blockIdx.x * blockDim.x + threadIdx.x) / 64;
    int lane = threadIdx.x % 64;
    if (wave >= rows) return;

    const float* r = in + (long)wave * cols;
    float v = (lane < cols) ? r[lane] : -INFINITY;

    float m = v;
    #pragma unroll
    for (int o = 32; o > 0; o >>= 1) m = fmaxf(m, __shfl_xor(m, o));

    float e = (lane < cols) ? __expf(v - m) : 0.0f;
    float s = e;
    #pragma unroll
    for (int o = 32; o > 0; o >>= 1) s += __shfl_xor(s, o);

    float ls = logf(s);
    if (lane < cols)
        out[(long)wave * cols + lane] = v - m - ls;
}

// ---------------------------------------------------------------------------
extern "C" void kernel_launch(void* const* d_in, const int* in_sizes, int n_in,
                              void* d_out, int out_size, void* d_ws, size_t ws_size,
                              hipStream_t stream)
{
    const float* x    = (const float*)d_in[0];
    const int*   src0 = (const int*)d_in[1];
    const int*   dst0 = (const int*)d_in[2];
    const int*   src1 = (const int*)d_in[3];
    const int*   dst1 = (const int*)d_in[4];
    const int*   src2 = (const int*)d_in[5];
    const int*   dst2 = (const int*)d_in[6];
    const float* Wl0  = (const float*)d_in[7];
    const float* Wr0  = (const float*)d_in[8];
    const float* b0   = (const float*)d_in[9];
    const float* Wl1  = (const float*)d_in[10];
    const float* Wr1  = (const float*)d_in[11];
    const float* b1   = (const float*)d_in[12];
    const float* Wl2  = (const float*)d_in[13];
    const float* Wr2  = (const float*)d_in[14];
    const float* b2   = (const float*)d_in[15];
    float* out = (float*)d_out;

    const int E0 = in_sizes[1];
    const int E1 = in_sizes[3];
    const int E2 = in_sizes[5];
    const int ETOT = E0 + E1 + E2;

    // Workspace layout (256B-aligned carve-outs)
    char* wp = (char*)d_ws;
    auto alloc = [&](size_t bytes) -> char* {
        char* p = wp; wp += (bytes + 255) & ~(size_t)255; return p;
    };
    __bf16* A0   = (__bf16*)alloc((size_t)N1 * K0P * 2);
    __bf16* h0   = (__bf16*)alloc((size_t)N1 * D_H * 2);
    __bf16* A1   = (__bf16*)alloc((size_t)N2 * K12P * 2);
    __bf16* h1   = (__bf16*)alloc((size_t)N2 * D_H * 2);
    __bf16* A2   = (__bf16*)alloc((size_t)NB * K12P * 2);
    float*  logits = (float*)alloc((size_t)NB * D_OUT * 4);
    __bf16* Wp0  = (__bf16*)alloc((size_t)256 * K0P * 2);
    __bf16* Wp1  = (__bf16*)alloc((size_t)256 * K12P * 2);
    __bf16* Wp2  = (__bf16*)alloc((size_t)128 * K12P * 2);
    int* deg      = (int*)alloc((size_t)NTOT * 4);
    int* cursor   = (int*)alloc((size_t)NTOT * 4);
    int* rowstart = (int*)alloc((size_t)(NTOT + 1) * 4);
    int* partials = (int*)alloc((size_t)SCAN_BLOCKS * 4);
    int* csr_src  = (int*)alloc((size_t)ETOT * 4);

    // Weight packing + batched CSR build (shared across all 3 layers)
    pack_weights_all<<<640, 256, 0, stream>>>(Wl0, Wr0, Wp0, Wl1, Wr1, Wp1, Wl2, Wr2, Wp2);
    hipMemsetAsync(deg, 0, (size_t)NTOT * 4, stream);
    hipMemsetAsync(cursor, 0, (size_t)NTOT * 4, stream);
    hist_all<<<(ETOT + 255) / 256, 256, 0, stream>>>(dst0, E0, dst1, E1, dst2, E2, deg);
    scan_partial<<<SCAN_BLOCKS, 256, 0, stream>>>(deg, partials, NTOT);
    scan_offsets<<<1, 256, 0, stream>>>(partials, rowstart, NTOT);
    scan_apply<<<SCAN_BLOCKS, 256, 0, stream>>>(deg, partials, rowstart, NTOT);
    scatter_all<<<(ETOT + 255) / 256, 256, 0, stream>>>(src0, dst0, E0, src1, dst1, E1,
                                                        src2, dst2, E2,
                                                        rowstart, cursor, csr_src);

    // ---------------- Layer 0 ----------------
    {
        int waves = (N1 + 3) / 4;
        gather_pack_l0<<<(waves + 3) / 4, 256, 0, stream>>>(x, rowstart, csr_src, A0, N1);
        dim3 grid((N1 + BM - 1) / BM, 1);
        mfma_gemm<256, 512><<<grid, 512, 0, stream>>>(A0, Wp0, b0, h0, nullptr,
                                                      N1, K0P, D_H, 1);
    }

    // ---------------- Layer 1 ----------------
    {
        gather_pack_h<<<(N2 + 3) / 4, 256, 0, stream>>>(h0, rowstart + N1, csr_src, A1, N2);
        dim3 grid((N2 + BM - 1) / BM, 2);
        mfma_gemm<128, 256><<<grid, 256, 0, stream>>>(A1, Wp1, b1, h1, nullptr,
                                                      N2, K12P, D_H, 1);
    }

    // ---------------- Layer 2 ----------------
    {
        gather_pack_h<<<(NB + 3) / 4, 256, 0, stream>>>(h1, rowstart + N1 + N2, csr_src, A2, NB);
        dim3 grid((NB + BM - 1) / BM, 1);
        mfma_gemm<128, 256><<<grid, 256, 0, stream>>>(A2, Wp2, b2, nullptr, logits,
                                                      NB, K12P, D_OUT, 0);
    }

    // ---------------- log_softmax ----------------
    {
        int waves_per_block = 256 / 64;
        int blocks = (NB + waves_per_block - 1) / waves_per_block;
        log_softmax_kernel<<<blocks, 256, 0, stream>>>(logits, out, NB, D_OUT);
    }
}

// Round 9
// 599.678 us; speedup vs baseline: 1.2439x; 1.2439x over previous
//
#include <hip/hip_runtime.h>
#include <hip/hip_bf16.h>

// ---------------------------------------------------------------------------
// Problem constants (fixed by the reference setup)
// ---------------------------------------------------------------------------
#define N0   1500000
#define N1   200000
#define N2   20000
#define NB   4096
#define D_IN 100
#define D_H  256
#define D_OUT 47

#define K0P  224   // padded K for layer 0 (100+100 -> 224, mult of 32)
#define K12P 512   // K for layers 1/2 (256+256)

#define NTOT (N1 + N2 + NB)     // concatenated row space (L0|L1|L2)
#define SCAN_BLOCKS 256

typedef __bf16 bf16x8 __attribute__((ext_vector_type(8)));
typedef __bf16 bf16x4 __attribute__((ext_vector_type(4)));
typedef float  f32x4  __attribute__((ext_vector_type(4)));

// ---------------------------------------------------------------------------
// Batched CSR build over all 3 layers: one histogram, one scan, one scatter.
// Row space concatenated L0|L1|L2.
// ---------------------------------------------------------------------------
__global__ void hist_all(const int* __restrict__ dst0, int E0,
                         const int* __restrict__ dst1, int E1,
                         const int* __restrict__ dst2, int E2,
                         int* __restrict__ deg)
{
    int i = blockIdx.x * blockDim.x + threadIdx.x;
    int t;
    if (i < E0)            t = dst0[i];
    else if (i < E0 + E1)  t = N1 + dst1[i - E0];
    else if (i < E0 + E1 + E2) t = N1 + N2 + dst2[i - E0 - E1];
    else return;
    atomicAdd(&deg[t], 1);
}

__global__ __launch_bounds__(256)
void scan_partial(const int* __restrict__ deg, int* __restrict__ partials, int n)
{
    const int b = blockIdx.x;
    const int chunk = (n + gridDim.x - 1) / gridDim.x;
    const int begin = b * chunk;
    const int end = min(begin + chunk, n);

    int s = 0;
    for (int i = begin + threadIdx.x; i < end; i += blockDim.x) s += deg[i];

    #pragma unroll
    for (int o = 32; o > 0; o >>= 1) s += __shfl_down(s, o);
    __shared__ int wsum[4];
    if ((threadIdx.x & 63) == 0) wsum[threadIdx.x >> 6] = s;
    __syncthreads();
    if (threadIdx.x == 0)
        partials[b] = wsum[0] + wsum[1] + wsum[2] + wsum[3];
}

__global__ __launch_bounds__(256)
void scan_offsets(int* __restrict__ partials, int* __restrict__ rowstart, int n)
{
    __shared__ int sm[256];
    const int t = threadIdx.x;
    sm[t] = partials[t];
    __syncthreads();
    for (int d = 1; d < 256; d <<= 1) {
        int val = sm[t];
        int oth = (t >= d) ? sm[t - d] : 0;
        __syncthreads();
        sm[t] = val + oth;
        __syncthreads();
    }
    partials[t] = (t > 0) ? sm[t - 1] : 0;
    if (t == 0) rowstart[n] = sm[255];
}

__global__ __launch_bounds__(256)
void scan_apply(const int* __restrict__ deg, const int* __restrict__ offsets,
                int* __restrict__ rowstart, int n)
{
    const int b = blockIdx.x;
    const int chunk = (n + gridDim.x - 1) / gridDim.x;
    const int begin = b * chunk;
    const int end = min(begin + chunk, n);

    __shared__ int sm[256];
    const int sub = (chunk + blockDim.x - 1) / blockDim.x;
    const int tb = begin + threadIdx.x * sub;
    const int te = min(tb + sub, end);

    int s = 0;
    for (int i = tb; i < te; ++i) s += deg[i];
    sm[threadIdx.x] = s;
    __syncthreads();
    for (int d = 1; d < 256; d <<= 1) {
        int val = sm[threadIdx.x];
        int oth = (threadIdx.x >= d) ? sm[threadIdx.x - d] : 0;
        __syncthreads();
        sm[threadIdx.x] = val + oth;
        __syncthreads();
    }
    int run = offsets[b] + ((threadIdx.x > 0) ? sm[threadIdx.x - 1] : 0);
    for (int i = tb; i < te; ++i) { rowstart[i] = run; run += deg[i]; }
}

__global__ void scatter_all(const int* __restrict__ src0, const int* __restrict__ dst0, int E0,
                            const int* __restrict__ src1, const int* __restrict__ dst1, int E1,
                            const int* __restrict__ src2, const int* __restrict__ dst2, int E2,
                            const int* __restrict__ rowstart,
                            int* __restrict__ cursor,
                            int* __restrict__ csr_src)
{
    int i = blockIdx.x * blockDim.x + threadIdx.x;
    int t, s;
    if (i < E0)                { t = dst0[i];                 s = src0[i]; }
    else if (i < E0 + E1)      { t = N1 + dst1[i - E0];       s = src1[i - E0]; }
    else if (i < E0 + E1 + E2) { t = N1 + N2 + dst2[i - E0 - E1]; s = src2[i - E0 - E1]; }
    else return;
    int pos = rowstart[t] + atomicAdd(&cursor[t], 1);
    csr_src[pos] = s;
}

// ---------------------------------------------------------------------------
// Layer-0 gather+pack (R7-proven shape): one wave per dst row, lanes 0..49
// own float2 pairs, flat x8/x4/x1 unroll ladder with ONE branch per batch —
// 8 independent row loads issue back-to-back. (R8's 4-row x 4-slot predicated
// form serialized the loads behind per-slot branches: 381 us vs this ~250.)
// ---------------------------------------------------------------------------
__global__ __launch_bounds__(256)
void gather_pack_l0(const float* __restrict__ x,
                    const int* __restrict__ rowstart,
                    const int* __restrict__ csr_src,
                    __bf16* __restrict__ A0, int nrows)
{
    const int wid  = (blockIdx.x * blockDim.x + threadIdx.x) >> 6;
    const int lane = threadIdx.x & 63;
    if (wid >= nrows) return;

    const int beg = rowstart[wid];
    const int end = rowstart[wid + 1];
    const bool act = lane < D_IN / 2;
    const int f = lane * 2;

    float ax[8], ay[8];
    #pragma unroll
    for (int u = 0; u < 8; ++u) { ax[u] = 0.0f; ay[u] = 0.0f; }

    int e = beg;
    for (; e + 8 <= end; e += 8) {
        int idx[8];
        #pragma unroll
        for (int u = 0; u < 8; ++u) idx[u] = csr_src[e + u];
        if (act) {
            float2 p[8];
            #pragma unroll
            for (int u = 0; u < 8; ++u)
                p[u] = *reinterpret_cast<const float2*>(x + (long)idx[u] * D_IN + f);
            #pragma unroll
            for (int u = 0; u < 8; ++u) { ax[u] += p[u].x; ay[u] += p[u].y; }
        }
    }
    for (; e + 4 <= end; e += 4) {
        int idx[4];
        #pragma unroll
        for (int u = 0; u < 4; ++u) idx[u] = csr_src[e + u];
        if (act) {
            float2 p[4];
            #pragma unroll
            for (int u = 0; u < 4; ++u)
                p[u] = *reinterpret_cast<const float2*>(x + (long)idx[u] * D_IN + f);
            #pragma unroll
            for (int u = 0; u < 4; ++u) { ax[u] += p[u].x; ay[u] += p[u].y; }
        }
    }
    for (; e < end; ++e) {
        int i0 = csr_src[e];
        if (act) {
            float2 p = *reinterpret_cast<const float2*>(x + (long)i0 * D_IN + f);
            ax[0] += p.x; ay[0] += p.y;
        }
    }

    const float inv = 1.0f / fmaxf((float)(end - beg), 1.0f);
    __bf16* o = A0 + (long)wid * K0P;
    const float* xd = x + (long)wid * D_IN;

    if (act) {
        float sx = ((ax[0] + ax[1]) + (ax[2] + ax[3])) + ((ax[4] + ax[5]) + (ax[6] + ax[7]));
        float sy = ((ay[0] + ay[1]) + (ay[2] + ay[3])) + ((ay[4] + ay[5]) + (ay[6] + ay[7]));
        o[f]     = (__bf16)(sx * inv);
        o[f + 1] = (__bf16)(sy * inv);
        float2 d = *reinterpret_cast<const float2*>(xd + f);
        o[D_IN + f]     = (__bf16)d.x;
        o[D_IN + f + 1] = (__bf16)d.y;
    }
    if (lane < K0P - 2 * D_IN) o[2 * D_IN + lane] = (__bf16)0.0f;
}

// ---------------------------------------------------------------------------
// Layers 1/2 gather+pack (D=256 bf16): Ap = [ mean | h ], unrolled x8.
// ---------------------------------------------------------------------------
__global__ __launch_bounds__(256)
void gather_pack_h(const __bf16* __restrict__ h,
                   const int* __restrict__ rowstart,
                   const int* __restrict__ csr_src,
                   __bf16* __restrict__ Ap, int nrows)
{
    const int wid  = (blockIdx.x * blockDim.x + threadIdx.x) >> 6;
    const int lane = threadIdx.x & 63;
    if (wid >= nrows) return;

    const int beg = rowstart[wid];
    const int end = rowstart[wid + 1];
    const __bf16* hf = h + lane * 4;

    float acc[8][4];
    #pragma unroll
    for (int u = 0; u < 8; ++u)
        #pragma unroll
        for (int k = 0; k < 4; ++k) acc[u][k] = 0.0f;

    int e = beg;
    for (; e + 8 <= end; e += 8) {
        int idx[8];
        #pragma unroll
        for (int u = 0; u < 8; ++u) idx[u] = csr_src[e + u];
        bf16x4 v[8];
        #pragma unroll
        for (int u = 0; u < 8; ++u)
            v[u] = *reinterpret_cast<const bf16x4*>(hf + (long)idx[u] * D_H);
        #pragma unroll
        for (int u = 0; u < 8; ++u)
            #pragma unroll
            for (int k = 0; k < 4; ++k) acc[u][k] += (float)v[u][k];
    }
    for (; e + 4 <= end; e += 4) {
        int idx[4];
        #pragma unroll
        for (int u = 0; u < 4; ++u) idx[u] = csr_src[e + u];
        bf16x4 v[4];
        #pragma unroll
        for (int u = 0; u < 4; ++u)
            v[u] = *reinterpret_cast<const bf16x4*>(hf + (long)idx[u] * D_H);
        #pragma unroll
        for (int u = 0; u < 4; ++u)
            #pragma unroll
            for (int k = 0; k < 4; ++k) acc[u][k] += (float)v[u][k];
    }
    for (; e < end; ++e) {
        bf16x4 v = *reinterpret_cast<const bf16x4*>(hf + (long)csr_src[e] * D_H);
        #pragma unroll
        for (int k = 0; k < 4; ++k) acc[0][k] += (float)v[k];
    }

    const float inv = 1.0f / fmaxf((float)(end - beg), 1.0f);
    bf16x4 m;
    #pragma unroll
    for (int k = 0; k < 4; ++k) {
        float s = ((acc[0][k] + acc[1][k]) + (acc[2][k] + acc[3][k]))
                + ((acc[4][k] + acc[5][k]) + (acc[6][k] + acc[7][k]));
        m[k] = (__bf16)(s * inv);
    }
    *reinterpret_cast<bf16x4*>(Ap + (long)wid * K12P + lane * 4) = m;

    bf16x4 own = *reinterpret_cast<const bf16x4*>(h + (long)wid * D_H + lane * 4);
    *reinterpret_cast<bf16x4*>(Ap + (long)wid * K12P + D_H + lane * 4) = own;
}

// ---------------------------------------------------------------------------
// Weight pack (all 3 layers in one launch): Wp[n][k] bf16, B^T layout.
// ---------------------------------------------------------------------------
__global__ void pack_weights_all(const float* __restrict__ Wl0, const float* __restrict__ Wr0, __bf16* __restrict__ Wp0,
                                 const float* __restrict__ Wl1, const float* __restrict__ Wr1, __bf16* __restrict__ Wp1,
                                 const float* __restrict__ Wl2, const float* __restrict__ Wr2, __bf16* __restrict__ Wp2)
{
    int b = blockIdx.x;
    const float* Wl; const float* Wr; __bf16* Wp;
    int K1, N, Kpad, n;
    if (b < 256)      { Wl = Wl0; Wr = Wr0; Wp = Wp0; K1 = D_IN; N = D_H;   Kpad = K0P;  n = b; }
    else if (b < 512) { Wl = Wl1; Wr = Wr1; Wp = Wp1; K1 = D_H;  N = D_H;   Kpad = K12P; n = b - 256; }
    else              { Wl = Wl2; Wr = Wr2; Wp = Wp2; K1 = D_H;  N = D_OUT; Kpad = K12P; n = b - 512; }

    for (int k = threadIdx.x; k < Kpad; k += blockDim.x) {
        float v = 0.0f;
        if (n < N) {
            if (k < K1)            v = Wl[(long)k * N + n];
            else if (k < 2 * K1)   v = Wr[(long)(k - K1) * N + n];
        }
        Wp[(long)n * Kpad + k] = (__bf16)v;
    }
}

// ---------------------------------------------------------------------------
// bf16 MFMA GEMM: C[M][Nreal] = act(A[M][K] @ Bt[Npad][K]^T + bias)
// Staging via global_load_lds dwordx4, linear LDS (proven R7, -24 us).
// ---------------------------------------------------------------------------
#define BM 128
#define BK 32

template <int BN_T, int NT>
__global__ __launch_bounds__(NT)
void mfma_gemm(const __bf16* __restrict__ A,
               const __bf16* __restrict__ Bt,
               const float* __restrict__ bias,
               __bf16* __restrict__ Cbf,
               float* __restrict__ Cf,
               int M, int K, int Nreal, int relu)
{
    constexpr int WC = (NT / 64) / 2;               // column waves
    static_assert(WC * 64 == BN_T, "wave grid must cover BN_T");
    constexpr int SIT = (BM + BN_T) * 4 / NT;       // staging iters (16B chunks)
    static_assert((BM * 4) % 64 == 0, "A/B staging boundary must be wave-aligned");

    __shared__ __bf16 S[(BM + BN_T) * BK];          // linear: row r at S[r*32]

    const int tid  = threadIdx.x;
    const int lane = tid & 63;
    const int wv   = tid >> 6;
    const int wr   = wv / WC;
    const int wc   = wv % WC;
    const long row0 = (long)blockIdx.x * BM;
    const int  col0 = blockIdx.y * BN_T;

    f32x4 acc[4][4] = {};

    for (int k0 = 0; k0 < K; k0 += BK) {
        __syncthreads();
        #pragma unroll
        for (int i = 0; i < SIT; ++i) {
            int c  = tid + i * NT;
            int r  = c >> 2;
            int ko = (c & 3) * 8;
            const __bf16* g;
            if (r < BM) {
                long gr = row0 + r;
                if (gr > M - 1) gr = M - 1;
                g = &A[gr * K + k0 + ko];
            } else {
                g = &Bt[(long)(col0 + (r - BM)) * K + k0 + ko];
            }
            __bf16* ldsb = &S[(size_t)(i * NT + wv * 64) * 8];
            __builtin_amdgcn_global_load_lds(
                (const __attribute__((address_space(1))) void*)g,
                (__attribute__((address_space(3))) void*)ldsb,
                16, 0, 0);
        }
        __syncthreads();

        bf16x8 a[4], b[4];
        #pragma unroll
        for (int mi = 0; mi < 4; ++mi)
            a[mi] = *reinterpret_cast<const bf16x8*>(
                &S[(wr * 64 + mi * 16 + (lane & 15)) * BK + (lane >> 4) * 8]);
        #pragma unroll
        for (int ni = 0; ni < 4; ++ni)
            b[ni] = *reinterpret_cast<const bf16x8*>(
                &S[(BM + wc * 64 + ni * 16 + (lane & 15)) * BK + (lane >> 4) * 8]);

        #pragma unroll
        for (int mi = 0; mi < 4; ++mi)
            #pragma unroll
            for (int ni = 0; ni < 4; ++ni)
                acc[mi][ni] = __builtin_amdgcn_mfma_f32_16x16x32_bf16(
                    a[mi], b[ni], acc[mi][ni], 0, 0, 0);
    }

    const int colBase = col0 + wc * 64;
    #pragma unroll
    for (int mi = 0; mi < 4; ++mi) {
        const long rowBase = row0 + wr * 64 + mi * 16 + (lane >> 4) * 4;
        #pragma unroll
        for (int j = 0; j < 4; ++j) {
            long r = rowBase + j;
            if (r >= M) continue;
            #pragma unroll
            for (int ni = 0; ni < 4; ++ni) {
                int cc = colBase + ni * 16 + (lane & 15);
                if (cc >= Nreal) continue;
                float v = acc[mi][ni][j] + bias[cc];
                if (relu) v = fmaxf(v, 0.0f);
                if (Cbf) Cbf[r * Nreal + cc] = (__bf16)v;
                else     Cf [r * Nreal + cc] = v;
            }
        }
    }
}

// ---------------------------------------------------------------------------
// Row-wise log_softmax: one wave per row, cols <= 64
// ---------------------------------------------------------------------------
__global__ void log_softmax_kernel(const float* __restrict__ in,
                                   float* __restrict__ out,
                                   int rows, int cols)
{
    int wave = (blockIdx.x * blockDim.x + threadIdx.x) / 64;
    int lane = threadIdx.x % 64;
    if (wave >= rows) return;

    const float* r = in + (long)wave * cols;
    float v = (lane < cols) ? r[lane] : -INFINITY;

    float m = v;
    #pragma unroll
    for (int o = 32; o > 0; o >>= 1) m = fmaxf(m, __shfl_xor(m, o));

    float e = (lane < cols) ? __expf(v - m) : 0.0f;
    float s = e;
    #pragma unroll
    for (int o = 32; o > 0; o >>= 1) s += __shfl_xor(s, o);

    float ls = logf(s);
    if (lane < cols)
        out[(long)wave * cols + lane] = v - m - ls;
}

// ---------------------------------------------------------------------------
extern "C" void kernel_launch(void* const* d_in, const int* in_sizes, int n_in,
                              void* d_out, int out_size, void* d_ws, size_t ws_size,
                              hipStream_t stream)
{
    const float* x    = (const float*)d_in[0];
    const int*   src0 = (const int*)d_in[1];
    const int*   dst0 = (const int*)d_in[2];
    const int*   src1 = (const int*)d_in[3];
    const int*   dst1 = (const int*)d_in[4];
    const int*   src2 = (const int*)d_in[5];
    const int*   dst2 = (const int*)d_in[6];
    const float* Wl0  = (const float*)d_in[7];
    const float* Wr0  = (const float*)d_in[8];
    const float* b0   = (const float*)d_in[9];
    const float* Wl1  = (const float*)d_in[10];
    const float* Wr1  = (const float*)d_in[11];
    const float* b1   = (const float*)d_in[12];
    const float* Wl2  = (const float*)d_in[13];
    const float* Wr2  = (const float*)d_in[14];
    const float* b2   = (const float*)d_in[15];
    float* out = (float*)d_out;

    const int E0 = in_sizes[1];
    const int E1 = in_sizes[3];
    const int E2 = in_sizes[5];
    const int ETOT = E0 + E1 + E2;

    // Workspace layout (256B-aligned carve-outs)
    char* wp = (char*)d_ws;
    auto alloc = [&](size_t bytes) -> char* {
        char* p = wp; wp += (bytes + 255) & ~(size_t)255; return p;
    };
    __bf16* A0   = (__bf16*)alloc((size_t)N1 * K0P * 2);
    __bf16* h0   = (__bf16*)alloc((size_t)N1 * D_H * 2);
    __bf16* A1   = (__bf16*)alloc((size_t)N2 * K12P * 2);
    __bf16* h1   = (__bf16*)alloc((size_t)N2 * D_H * 2);
    __bf16* A2   = (__bf16*)alloc((size_t)NB * K12P * 2);
    float*  logits = (float*)alloc((size_t)NB * D_OUT * 4);
    __bf16* Wp0  = (__bf16*)alloc((size_t)256 * K0P * 2);
    __bf16* Wp1  = (__bf16*)alloc((size_t)256 * K12P * 2);
    __bf16* Wp2  = (__bf16*)alloc((size_t)128 * K12P * 2);
    int* deg      = (int*)alloc((size_t)NTOT * 4);
    int* cursor   = (int*)alloc((size_t)NTOT * 4);
    int* rowstart = (int*)alloc((size_t)(NTOT + 1) * 4);
    int* partials = (int*)alloc((size_t)SCAN_BLOCKS * 4);
    int* csr_src  = (int*)alloc((size_t)ETOT * 4);

    // Weight packing + batched CSR build (shared across all 3 layers)
    pack_weights_all<<<640, 256, 0, stream>>>(Wl0, Wr0, Wp0, Wl1, Wr1, Wp1, Wl2, Wr2, Wp2);
    hipMemsetAsync(deg, 0, (size_t)NTOT * 4, stream);
    hipMemsetAsync(cursor, 0, (size_t)NTOT * 4, stream);
    hist_all<<<(ETOT + 255) / 256, 256, 0, stream>>>(dst0, E0, dst1, E1, dst2, E2, deg);
    scan_partial<<<SCAN_BLOCKS, 256, 0, stream>>>(deg, partials, NTOT);
    scan_offsets<<<1, 256, 0, stream>>>(partials, rowstart, NTOT);
    scan_apply<<<SCAN_BLOCKS, 256, 0, stream>>>(deg, partials, rowstart, NTOT);
    scatter_all<<<(ETOT + 255) / 256, 256, 0, stream>>>(src0, dst0, E0, src1, dst1, E1,
                                                        src2, dst2, E2,
                                                        rowstart, cursor, csr_src);

    // ---------------- Layer 0 ----------------
    {
        gather_pack_l0<<<(N1 + 3) / 4, 256, 0, stream>>>(x, rowstart, csr_src, A0, N1);
        dim3 grid((N1 + BM - 1) / BM, 1);
        mfma_gemm<256, 512><<<grid, 512, 0, stream>>>(A0, Wp0, b0, h0, nullptr,
                                                      N1, K0P, D_H, 1);
    }

    // ---------------- Layer 1 ----------------
    {
        gather_pack_h<<<(N2 + 3) / 4, 256, 0, stream>>>(h0, rowstart + N1, csr_src, A1, N2);
        dim3 grid((N2 + BM - 1) / BM, 2);
        mfma_gemm<128, 256><<<grid, 256, 0, stream>>>(A1, Wp1, b1, h1, nullptr,
                                                      N2, K12P, D_H, 1);
    }

    // ---------------- Layer 2 ----------------
    {
        gather_pack_h<<<(NB + 3) / 4, 256, 0, stream>>>(h1, rowstart + N1 + N2, csr_src, A2, NB);
        dim3 grid((NB + BM - 1) / BM, 1);
        mfma_gemm<128, 256><<<grid, 256, 0, stream>>>(A2, Wp2, b2, nullptr, logits,
                                                      NB, K12P, D_OUT, 0);
    }

    // ---------------- log_softmax ----------------
    {
        int waves_per_block = 256 / 64;
        int blocks = (NB + waves_per_block - 1) / waves_per_block;
        log_softmax_kernel<<<blocks, 256, 0, stream>>>(logits, out, NB, D_OUT);
    }
}